// Round 3
// baseline (686.062 us; speedup 1.0000x reference)
//
#include <hip/hip_runtime.h>

// DGCF single-layer, 2 routing iters (MI355X). fp32 in / fp32 out.
// Simplifications proved in analysis:
//  - iter0 softmax(ones)=0.25 exactly -> deg0 = 0.25*head_degree (intent-independent)
//  - l2norm scale-invariance -> iter0's Z kept unscaled (d_col*Z skipped before attn)
//  - iter1's A_values update is dead code (never read) -> skipped
//  - iter1's d_col*Z folded into the output kernel
// Workspace (fp32): Z[N][64], scores[E][4], dcol[N][4], deg[N][4], invnZ[N][4],
// invnX[N][4] -> exactly 32,000,000 bytes.

#define NUSERS 30000
#define NN     60000
#define EE     800000

__device__ __forceinline__ float getX(const float* __restrict__ Gu,
                                      const float* __restrict__ Gi,
                                      int n, int c) {
    return (n < NUSERS) ? Gu[n * 64 + c] : Gi[(n - NUSERS) * 64 + c];
}

__device__ __forceinline__ int clampN(int n) {
    return ((unsigned)n < (unsigned)NN) ? n : 0;   // defensive: no-op for valid input
}

__global__ void edge_count(const int* __restrict__ eh, float* __restrict__ deg) {
    int e = blockIdx.x * blockDim.x + threadIdx.x;
    if (e >= EE) return;
    atomicAdd(&deg[clampN(eh[e]) * 4], 1.0f);
}

__global__ void node_dcol0(const float* __restrict__ deg, float* __restrict__ dcol) {
    int n = blockIdx.x * blockDim.x + threadIdx.x;
    if (n >= NN) return;
    float d = rsqrtf(fmaxf(0.25f * deg[n * 4], 1e-30f));
    dcol[n * 4 + 0] = d; dcol[n * 4 + 1] = d; dcol[n * 4 + 2] = d; dcol[n * 4 + 3] = d;
}

// One wave64 per edge; lane k = channel k, intent i = k>>4.
template <bool UNIFORM>
__global__ void edge_prop(const int* __restrict__ eh, const int* __restrict__ et,
                          const float* __restrict__ Gu, const float* __restrict__ Gi,
                          const float* __restrict__ dcol,
                          const float* __restrict__ scores, float* __restrict__ Z) {
    int e = blockIdx.x * 4 + (threadIdx.x >> 6);
    if (e >= EE) return;
    int lane = threadIdx.x & 63;
    int i = lane >> 4;
    int h = clampN(eh[e]), t = clampN(et[e]);
    float s = UNIFORM ? 0.25f : scores[e * 4 + i];
    float val = s * dcol[t * 4 + i] * getX(Gu, Gi, t, lane);
    atomicAdd(&Z[h * 64 + lane], val);
}

// Wave64 per node: per-intent inverse norms of Z1 (unscaled ok) and of X.
__global__ void node_prep(const float* __restrict__ Gu, const float* __restrict__ Gi,
                          const float* __restrict__ Z,
                          float* __restrict__ invnZ, float* __restrict__ invnX) {
    int n = blockIdx.x * 4 + (threadIdx.x >> 6);
    if (n >= NN) return;
    int lane = threadIdx.x & 63;
    int i = lane >> 4;
    float z = Z[n * 64 + lane];
    float x = getX(Gu, Gi, n, lane);
    float sz = z * z, sx = x * x;
    #pragma unroll
    for (int m = 1; m < 16; m <<= 1) {
        sz += __shfl_xor(sz, m, 64);
        sx += __shfl_xor(sx, m, 64);
    }
    if ((lane & 15) == 0) {
        invnZ[n * 4 + i] = rsqrtf(fmaxf(sz, 1e-12f));
        invnX[n * 4 + i] = rsqrtf(fmaxf(sx, 1e-12f));
    }
}

// Wave64 per edge: v_i = l2norm(Z1[h])_i . tanh(l2norm(X[t]))_i, softmax over
// the 4 intents, emit scores + per-intent deg scatter. (+1 bias of A cancels.)
__global__ void edge_attn(const int* __restrict__ eh, const int* __restrict__ et,
                          const float* __restrict__ Gu, const float* __restrict__ Gi,
                          const float* __restrict__ Z,
                          const float* __restrict__ invnZ, const float* __restrict__ invnX,
                          float* __restrict__ scores, float* __restrict__ deg) {
    int e = blockIdx.x * 4 + (threadIdx.x >> 6);
    if (e >= EE) return;
    int lane = threadIdx.x & 63;
    int i = lane >> 4;
    int h = clampN(eh[e]), t = clampN(et[e]);
    float xt = getX(Gu, Gi, t, lane);
    float tn = tanhf(xt * invnX[t * 4 + i]);
    float p = Z[h * 64 + lane] * tn;
    #pragma unroll
    for (int m = 1; m < 16; m <<= 1) p += __shfl_xor(p, m, 64);
    float v = p * invnZ[h * 4 + i];
    float mx = fmaxf(v, __shfl_xor(v, 16, 64));
    mx = fmaxf(mx, __shfl_xor(mx, 32, 64));
    float ev = __expf(v - mx);
    float se = ev + __shfl_xor(ev, 16, 64);
    se += __shfl_xor(se, 32, 64);
    float s = ev / se;
    if ((lane & 15) == 0) {
        scores[e * 4 + i] = s;
        atomicAdd(&deg[h * 4 + i], s);
    }
}

__global__ void node_dcol1(const float* __restrict__ deg, float* __restrict__ dcol) {
    int idx = blockIdx.x * blockDim.x + threadIdx.x;
    if (idx >= NN * 4) return;
    dcol[idx] = rsqrtf(fmaxf(deg[idx], 1e-30f));
}

__global__ void finalize(const float* __restrict__ Gu, const float* __restrict__ Gi,
                         const float* __restrict__ Z, const float* __restrict__ dcol,
                         float* __restrict__ out) {
    int idx = blockIdx.x * blockDim.x + threadIdx.x;
    if (idx >= NN * 64) return;
    int n = idx >> 6, i = (idx >> 4) & 3;
    float x = getX(Gu, Gi, n, idx & 63);
    out[idx] = 0.5f * (x + dcol[n * 4 + i] * Z[idx]);
}

extern "C" void kernel_launch(void* const* d_in, const int* in_sizes, int n_in,
                              void* d_out, int out_size, void* d_ws, size_t ws_size,
                              hipStream_t stream) {
    const float* Gu = (const float*)d_in[0];
    const float* Gi = (const float*)d_in[1];
    const int* eh = (const int*)d_in[2];
    const int* et = (const int*)d_in[3];
    float* out = (float*)d_out;

    float* ws     = (float*)d_ws;
    float* Z      = ws;                  // N*64 = 3,840,000 f
    float* scores = Z + NN * 64;         // E*4  = 3,200,000 f
    float* dcol   = scores + EE * 4;     // N*4
    float* deg    = dcol + NN * 4;       // N*4
    float* invnZ  = deg + NN * 4;        // N*4
    float* invnX  = invnZ + NN * 4;      // N*4
    // total: 8,000,000 floats = 32,000,000 bytes

    const int nk_blocks   = (NN * 64 + 255) / 256;
    const int edge_blocks = (EE + 255) / 256;
    const int node_blocks = (NN + 255) / 256;
    const int n4_blocks   = (NN * 4 + 255) / 256;
    const int ew_blocks   = (EE + 3) / 4;   // wave-per-edge
    const int nw_blocks   = (NN + 3) / 4;   // wave-per-node

    // ---- routing iter 0 (uniform scores = 0.25) ----
    hipMemsetAsync(deg, 0, NN * 4 * sizeof(float), stream);
    hipMemsetAsync(Z, 0, NN * 64 * sizeof(float), stream);
    edge_count<<<edge_blocks, 256, 0, stream>>>(eh, deg);
    node_dcol0<<<node_blocks, 256, 0, stream>>>(deg, dcol);
    edge_prop<true><<<ew_blocks, 256, 0, stream>>>(eh, et, Gu, Gi, dcol, nullptr, Z);
    node_prep<<<nw_blocks, 256, 0, stream>>>(Gu, Gi, Z, invnZ, invnX);

    // ---- attention update -> iter 1 scores + deg ----
    hipMemsetAsync(deg, 0, NN * 4 * sizeof(float), stream);
    edge_attn<<<ew_blocks, 256, 0, stream>>>(eh, et, Gu, Gi, Z, invnZ, invnX, scores, deg);

    // ---- routing iter 1 propagate ----
    node_dcol1<<<n4_blocks, 256, 0, stream>>>(deg, dcol);
    hipMemsetAsync(Z, 0, NN * 64 * sizeof(float), stream);
    edge_prop<false><<<ew_blocks, 256, 0, stream>>>(eh, et, Gu, Gi, dcol, scores, Z);

    // ---- output: (X + dcol*Z2)/2 ----
    finalize<<<nk_blocks, 256, 0, stream>>>(Gu, Gi, Z, dcol, out);
}

// Round 4
// 654.771 us; speedup vs baseline: 1.0478x; 1.0478x over previous
//
#include <hip/hip_runtime.h>
#include <hip/hip_fp16.h>

// DGCF single-layer, 2 routing iters (MI355X). fp32 in / fp32 out.
// R3: edge_attn was VALU-bound (75%) on per-edge tanhf (51.2M evals, 13.3x
// redundant) + 512 B/edge fp32 gathers. Fix: precompute per-node fp16 tables
//   Zn = l2norm(Z1)  Tn = tanh(l2norm(X))  Y = dcol (.) X
// so edge kernels gather 128 B/edge/table and do no transcendentals.
// Fancy path needs 46.72 MB ws; falls back to the 32.0 MB fp32 layout
// (R3's passing kernel) if ws_size is smaller. Branch is on ws_size only,
// constant across calls -> graph-capture safe.

#define NUSERS 30000
#define NN     60000
#define EE     800000

__device__ __forceinline__ float getX(const float* __restrict__ Gu,
                                      const float* __restrict__ Gi,
                                      int n, int c) {
    return (n < NUSERS) ? Gu[n * 64 + c] : Gi[(n - NUSERS) * 64 + c];
}

__device__ __forceinline__ int clampN(int n) {
    return ((unsigned)n < (unsigned)NN) ? n : 0;   // defensive: no-op for valid input
}

// ---------------- shared small kernels ----------------

__global__ void edge_count(const int* __restrict__ eh, float* __restrict__ deg) {
    int e = blockIdx.x * blockDim.x + threadIdx.x;
    if (e >= EE) return;
    atomicAdd(&deg[clampN(eh[e]) * 4], 1.0f);
}

__global__ void node_dcol0(const float* __restrict__ deg, float* __restrict__ dcol) {
    int n = blockIdx.x * blockDim.x + threadIdx.x;
    if (n >= NN) return;
    float d = rsqrtf(fmaxf(0.25f * deg[n * 4], 1e-30f));
    dcol[n * 4 + 0] = d; dcol[n * 4 + 1] = d; dcol[n * 4 + 2] = d; dcol[n * 4 + 3] = d;
}

__global__ void node_dcol1(const float* __restrict__ deg, float* __restrict__ dcol) {
    int idx = blockIdx.x * blockDim.x + threadIdx.x;
    if (idx >= NN * 4) return;
    dcol[idx] = rsqrtf(fmaxf(deg[idx], 1e-30f));
}

__global__ void finalize(const float* __restrict__ Gu, const float* __restrict__ Gi,
                         const float* __restrict__ Z, const float* __restrict__ dcol,
                         float* __restrict__ out) {
    int idx = blockIdx.x * blockDim.x + threadIdx.x;
    if (idx >= NN * 64) return;
    int n = idx >> 6, i = (idx >> 4) & 3;
    float x = getX(Gu, Gi, n, idx & 63);
    out[idx] = 0.5f * (x + dcol[n * 4 + i] * Z[idx]);
}

// ---------------- fancy path (fp16 gather tables) ----------------

// Y[n][c] = dcol[n][c>>4] * X[n][c]  (fp16)
__global__ void build_Y(const float* __restrict__ Gu, const float* __restrict__ Gi,
                        const float* __restrict__ dcol, __half* __restrict__ Y) {
    int idx = blockIdx.x * blockDim.x + threadIdx.x;
    if (idx >= NN * 64) return;
    int n = idx >> 6, i = (idx >> 4) & 3;
    Y[idx] = __float2half(dcol[n * 4 + i] * getX(Gu, Gi, n, idx & 63));
}

// One wave64 per edge; lane k = channel k, intent i = k>>4.
template <bool UNIFORM>
__global__ void edge_prop2(const int* __restrict__ eh, const int* __restrict__ et,
                           const __half* __restrict__ Y,
                           const __half* __restrict__ scores_h,
                           float* __restrict__ Z) {
    int e = blockIdx.x * 4 + (threadIdx.x >> 6);
    if (e >= EE) return;
    int lane = threadIdx.x & 63;
    int h = clampN(eh[e]), t = clampN(et[e]);
    float s = UNIFORM ? 0.25f : __half2float(scores_h[e * 4 + (lane >> 4)]);
    float val = s * __half2float(Y[t * 64 + lane]);
    atomicAdd(&Z[h * 64 + lane], val);
}

// Wave64 per node: Zn = Z/|Z|_intent, Tn = tanh(X/|X|_intent), fp16.
__global__ void node_prep2(const float* __restrict__ Gu, const float* __restrict__ Gi,
                           const float* __restrict__ Z,
                           __half* __restrict__ Zn, __half* __restrict__ Tn) {
    int n = blockIdx.x * 4 + (threadIdx.x >> 6);
    if (n >= NN) return;
    int lane = threadIdx.x & 63;
    float z = Z[n * 64 + lane];
    float x = getX(Gu, Gi, n, lane);
    float sz = z * z, sx = x * x;
    #pragma unroll
    for (int m = 1; m < 16; m <<= 1) {
        sz += __shfl_xor(sz, m, 64);
        sx += __shfl_xor(sx, m, 64);
    }
    float invz = rsqrtf(fmaxf(sz, 1e-12f));
    float invx = rsqrtf(fmaxf(sx, 1e-12f));
    Zn[n * 64 + lane] = __float2half(z * invz);
    Tn[n * 64 + lane] = __float2half(tanhf(x * invx));
}

// Wave64 per edge: v_i = Zn[h]_i . Tn[t]_i, softmax over 4 intents,
// emit fp16 scores + per-intent deg scatter. (+1 bias of A cancels.)
__global__ void edge_attn2(const int* __restrict__ eh, const int* __restrict__ et,
                           const __half* __restrict__ Zn, const __half* __restrict__ Tn,
                           __half* __restrict__ scores_h, float* __restrict__ deg) {
    int e = blockIdx.x * 4 + (threadIdx.x >> 6);
    if (e >= EE) return;
    int lane = threadIdx.x & 63;
    int i = lane >> 4;
    int h = clampN(eh[e]), t = clampN(et[e]);
    float p = __half2float(Zn[h * 64 + lane]) * __half2float(Tn[t * 64 + lane]);
    #pragma unroll
    for (int m = 1; m < 16; m <<= 1) p += __shfl_xor(p, m, 64);
    float mx = fmaxf(p, __shfl_xor(p, 16, 64));
    mx = fmaxf(mx, __shfl_xor(mx, 32, 64));
    float ev = __expf(p - mx);
    float se = ev + __shfl_xor(ev, 16, 64);
    se += __shfl_xor(se, 32, 64);
    float s = ev / se;
    if ((lane & 15) == 0) {
        scores_h[e * 4 + i] = __float2half(s);
        atomicAdd(&deg[h * 4 + i], s);
    }
}

// ---------------- legacy path (32 MB, pure fp32 — R3's passing kernel) ----------------

template <bool UNIFORM>
__global__ void edge_prop(const int* __restrict__ eh, const int* __restrict__ et,
                          const float* __restrict__ Gu, const float* __restrict__ Gi,
                          const float* __restrict__ dcol,
                          const float* __restrict__ scores, float* __restrict__ Z) {
    int e = blockIdx.x * 4 + (threadIdx.x >> 6);
    if (e >= EE) return;
    int lane = threadIdx.x & 63;
    int i = lane >> 4;
    int h = clampN(eh[e]), t = clampN(et[e]);
    float s = UNIFORM ? 0.25f : scores[e * 4 + i];
    float val = s * dcol[t * 4 + i] * getX(Gu, Gi, t, lane);
    atomicAdd(&Z[h * 64 + lane], val);
}

__global__ void node_prep(const float* __restrict__ Gu, const float* __restrict__ Gi,
                          const float* __restrict__ Z,
                          float* __restrict__ invnZ, float* __restrict__ invnX) {
    int n = blockIdx.x * 4 + (threadIdx.x >> 6);
    if (n >= NN) return;
    int lane = threadIdx.x & 63;
    int i = lane >> 4;
    float z = Z[n * 64 + lane];
    float x = getX(Gu, Gi, n, lane);
    float sz = z * z, sx = x * x;
    #pragma unroll
    for (int m = 1; m < 16; m <<= 1) {
        sz += __shfl_xor(sz, m, 64);
        sx += __shfl_xor(sx, m, 64);
    }
    if ((lane & 15) == 0) {
        invnZ[n * 4 + i] = rsqrtf(fmaxf(sz, 1e-12f));
        invnX[n * 4 + i] = rsqrtf(fmaxf(sx, 1e-12f));
    }
}

__global__ void edge_attn(const int* __restrict__ eh, const int* __restrict__ et,
                          const float* __restrict__ Gu, const float* __restrict__ Gi,
                          const float* __restrict__ Z,
                          const float* __restrict__ invnZ, const float* __restrict__ invnX,
                          float* __restrict__ scores, float* __restrict__ deg) {
    int e = blockIdx.x * 4 + (threadIdx.x >> 6);
    if (e >= EE) return;
    int lane = threadIdx.x & 63;
    int i = lane >> 4;
    int h = clampN(eh[e]), t = clampN(et[e]);
    float xt = getX(Gu, Gi, t, lane);
    float tn = tanhf(xt * invnX[t * 4 + i]);
    float p = Z[h * 64 + lane] * tn;
    #pragma unroll
    for (int m = 1; m < 16; m <<= 1) p += __shfl_xor(p, m, 64);
    float v = p * invnZ[h * 4 + i];
    float mx = fmaxf(v, __shfl_xor(v, 16, 64));
    mx = fmaxf(mx, __shfl_xor(mx, 32, 64));
    float ev = __expf(v - mx);
    float se = ev + __shfl_xor(ev, 16, 64);
    se += __shfl_xor(se, 32, 64);
    float s = ev / se;
    if ((lane & 15) == 0) {
        scores[e * 4 + i] = s;
        atomicAdd(&deg[h * 4 + i], s);
    }
}

// ---------------- launch ----------------

extern "C" void kernel_launch(void* const* d_in, const int* in_sizes, int n_in,
                              void* d_out, int out_size, void* d_ws, size_t ws_size,
                              hipStream_t stream) {
    const float* Gu = (const float*)d_in[0];
    const float* Gi = (const float*)d_in[1];
    const int* eh = (const int*)d_in[2];
    const int* et = (const int*)d_in[3];
    float* out = (float*)d_out;

    const int nk_blocks   = (NN * 64 + 255) / 256;
    const int edge_blocks = (EE + 255) / 256;
    const int node_blocks = (NN + 255) / 256;
    const int n4_blocks   = (NN * 4 + 255) / 256;
    const int ew_blocks   = (EE + 3) / 4;   // wave-per-edge
    const int nw_blocks   = (NN + 3) / 4;   // wave-per-node

    // Fancy layout: Z f32 + Zn/Tn/Y fp16 + scores fp16 + dcol/deg f32
    const size_t FANCY_BYTES =
        (size_t)NN * 64 * 4 + 3 * (size_t)NN * 64 * 2 + (size_t)EE * 4 * 2
        + 2 * (size_t)NN * 4 * 4;   // 46,720,000

    if (ws_size >= FANCY_BYTES) {
        char* p = (char*)d_ws;
        float*  Z        = (float*)p;              p += (size_t)NN * 64 * 4;
        __half* Zn       = (__half*)p;             p += (size_t)NN * 64 * 2;
        __half* Tn       = (__half*)p;             p += (size_t)NN * 64 * 2;
        __half* Y        = (__half*)p;             p += (size_t)NN * 64 * 2;
        __half* scores_h = (__half*)p;             p += (size_t)EE * 4 * 2;
        float*  dcol     = (float*)p;              p += (size_t)NN * 4 * 4;
        float*  deg      = (float*)p;

        hipMemsetAsync(deg, 0, NN * 4 * sizeof(float), stream);
        hipMemsetAsync(Z, 0, NN * 64 * sizeof(float), stream);
        edge_count<<<edge_blocks, 256, 0, stream>>>(eh, deg);
        node_dcol0<<<node_blocks, 256, 0, stream>>>(deg, dcol);
        build_Y<<<nk_blocks, 256, 0, stream>>>(Gu, Gi, dcol, Y);
        edge_prop2<true><<<ew_blocks, 256, 0, stream>>>(eh, et, Y, nullptr, Z);
        node_prep2<<<nw_blocks, 256, 0, stream>>>(Gu, Gi, Z, Zn, Tn);

        hipMemsetAsync(deg, 0, NN * 4 * sizeof(float), stream);
        edge_attn2<<<ew_blocks, 256, 0, stream>>>(eh, et, Zn, Tn, scores_h, deg);

        node_dcol1<<<n4_blocks, 256, 0, stream>>>(deg, dcol);
        build_Y<<<nk_blocks, 256, 0, stream>>>(Gu, Gi, dcol, Y);
        hipMemsetAsync(Z, 0, NN * 64 * sizeof(float), stream);
        edge_prop2<false><<<ew_blocks, 256, 0, stream>>>(eh, et, Y, scores_h, Z);

        finalize<<<nk_blocks, 256, 0, stream>>>(Gu, Gi, Z, dcol, out);
    } else {
        // legacy 32.0 MB fp32 path (R3 passing)
        float* ws     = (float*)d_ws;
        float* Z      = ws;
        float* scores = Z + NN * 64;
        float* dcol   = scores + EE * 4;
        float* deg    = dcol + NN * 4;
        float* invnZ  = deg + NN * 4;
        float* invnX  = invnZ + NN * 4;

        hipMemsetAsync(deg, 0, NN * 4 * sizeof(float), stream);
        hipMemsetAsync(Z, 0, NN * 64 * sizeof(float), stream);
        edge_count<<<edge_blocks, 256, 0, stream>>>(eh, deg);
        node_dcol0<<<node_blocks, 256, 0, stream>>>(deg, dcol);
        edge_prop<true><<<ew_blocks, 256, 0, stream>>>(eh, et, Gu, Gi, dcol, nullptr, Z);
        node_prep<<<nw_blocks, 256, 0, stream>>>(Gu, Gi, Z, invnZ, invnX);

        hipMemsetAsync(deg, 0, NN * 4 * sizeof(float), stream);
        edge_attn<<<ew_blocks, 256, 0, stream>>>(eh, et, Gu, Gi, Z, invnZ, invnX, scores, deg);

        node_dcol1<<<n4_blocks, 256, 0, stream>>>(deg, dcol);
        hipMemsetAsync(Z, 0, NN * 64 * sizeof(float), stream);
        edge_prop<false><<<ew_blocks, 256, 0, stream>>>(eh, et, Gu, Gi, dcol, scores, Z);

        finalize<<<nk_blocks, 256, 0, stream>>>(Gu, Gi, Z, dcol, out);
    }
}

// Round 5
// 492.989 us; speedup vs baseline: 1.3916x; 1.3282x over previous
//
#include <hip/hip_runtime.h>
#include <hip/hip_fp16.h>

// DGCF single-layer, 2 routing iters (MI355X). fp32 in / fp32 out.
// R4 post-mortem: edge-parallel scatter was ATOMIC-bound (WRITE_SIZE == exact
// atomic volume: fp32 atomics write through memory-side; 293G atomics/s cap,
// VALU 19%, HBM 20%). R5: counting-sort edges by head into CSR on device,
// then all edge work is one-wave-per-node gather loops with register
// accumulation -- zero fp32 atomics, Z never materialized.
//   prep0 : Tn = tanh(l2norm(X)) fp16, Y0 = dcol0*X fp16   (wave/node)
//   fused0: Z1[h] = 0.25*sum Y0[t] (regs) -> l2norm -> attn dots vs Tn[t]
//           -> softmax(4) -> scores_csr fp16 + deg[h][4]   (wave/node)
//   fused1: Z2[h] = sum s*Y1[t] -> out = 0.5*(X + dcol1*Z2) (wave/node)
// Workspace 27.6 MB (ws proven >= 32 MB in R3/R4). All buffers written
// before read each call (ws is re-poisoned); CSR intra-segment order is
// nondeterministic but consistent within a call (built once, read thrice).

#define NUSERS 30000
#define NN     60000
#define EE     800000

__device__ __forceinline__ float getX(const float* __restrict__ Gu,
                                      const float* __restrict__ Gi,
                                      int n, int c) {
    return (n < NUSERS) ? Gu[n * 64 + c] : Gi[(n - NUSERS) * 64 + c];
}

__device__ __forceinline__ int clampN(int n) {
    return ((unsigned)n < (unsigned)NN) ? n : 0;   // defensive: no-op for valid input
}

// ---- CSR build ----

__global__ void edge_count(const int* __restrict__ eh, int* __restrict__ deg0) {
    int e = blockIdx.x * blockDim.x + threadIdx.x;
    if (e >= EE) return;
    atomicAdd(&deg0[clampN(eh[e])], 1);
}

// Single-block exclusive scan of deg0[NN] -> offsets[NN+1].
__global__ void scan_offsets(const int* __restrict__ deg0, int* __restrict__ offsets) {
    __shared__ int sums[1024];
    const int CH = (NN + 1023) / 1024;   // 59
    int tid = threadIdx.x;
    int base = tid * CH;
    int s = 0;
    for (int j = 0; j < CH; ++j) {
        int idx = base + j;
        if (idx < NN) s += deg0[idx];
    }
    sums[tid] = s;
    __syncthreads();
    for (int off = 1; off < 1024; off <<= 1) {
        int v = (tid >= off) ? sums[tid - off] : 0;
        __syncthreads();
        sums[tid] += v;
        __syncthreads();
    }
    int run = (tid == 0) ? 0 : sums[tid - 1];
    for (int j = 0; j < CH; ++j) {
        int idx = base + j;
        if (idx < NN) { offsets[idx] = run; run += deg0[idx]; }
    }
    if (tid == 1023) offsets[NN] = sums[1023];
}

__global__ void edge_scatter(const int* __restrict__ eh, const int* __restrict__ et,
                             const int* __restrict__ offsets, int* __restrict__ cursor,
                             int* __restrict__ csr_tail) {
    int e = blockIdx.x * blockDim.x + threadIdx.x;
    if (e >= EE) return;
    int h = clampN(eh[e]);
    int slot = offsets[h] + atomicAdd(&cursor[h], 1);
    if (slot < EE) csr_tail[slot] = clampN(et[e]);
}

// ---- node-side precompute ----

// Wave per node: Tn = tanh(x/|x|_intent) fp16, Y0 = dcol0 * x fp16.
__global__ void prep0(const float* __restrict__ Gu, const float* __restrict__ Gi,
                      const int* __restrict__ deg0,
                      __half* __restrict__ Tn, __half* __restrict__ Y) {
    int n = blockIdx.x * 4 + (threadIdx.x >> 6);
    if (n >= NN) return;
    int lane = threadIdx.x & 63;
    float x = getX(Gu, Gi, n, lane);
    float sx = x * x;
    #pragma unroll
    for (int m = 1; m < 16; m <<= 1) sx += __shfl_xor(sx, m, 64);
    float invx = rsqrtf(fmaxf(sx, 1e-12f));
    Tn[n * 64 + lane] = __float2half(tanhf(x * invx));
    float d0 = rsqrtf(fmaxf(0.25f * (float)deg0[n], 1e-30f));
    Y[n * 64 + lane] = __float2half(d0 * x);
}

__global__ void node_dcol1(const float* __restrict__ deg, float* __restrict__ dcol) {
    int idx = blockIdx.x * blockDim.x + threadIdx.x;
    if (idx >= NN * 4) return;
    dcol[idx] = rsqrtf(fmaxf(deg[idx], 1e-30f));
}

// Y1 = dcol1(intent) * x  fp16
__global__ void build_Y1(const float* __restrict__ Gu, const float* __restrict__ Gi,
                         const float* __restrict__ dcol, __half* __restrict__ Y) {
    int idx = blockIdx.x * blockDim.x + threadIdx.x;
    if (idx >= NN * 64) return;
    int n = idx >> 6, i = (idx >> 4) & 3;
    Y[idx] = __float2half(dcol[n * 4 + i] * getX(Gu, Gi, n, idx & 63));
}

// ---- fused node-parallel edge passes ----

// Wave per node h: Z1 gather (regs) -> l2norm -> attn vs Tn[t] -> softmax ->
// scores_csr fp16 (CSR order) + deg[h][4] (plain store).
__global__ void fused0(const int* __restrict__ offsets, const int* __restrict__ csr_tail,
                       const __half* __restrict__ Y, const __half* __restrict__ Tn,
                       __half* __restrict__ scores, float* __restrict__ deg) {
    int n = blockIdx.x * 4 + (threadIdx.x >> 6);
    if (n >= NN) return;
    int lane = threadIdx.x & 63;
    int i = lane >> 4;
    int s0 = offsets[n], s1 = offsets[n + 1];

    float acc = 0.f;
    int k = s0;
    for (; k + 1 < s1; k += 2) {
        int t0 = csr_tail[k], t1 = csr_tail[k + 1];
        float a = __half2float(Y[t0 * 64 + lane]);
        float b = __half2float(Y[t1 * 64 + lane]);
        acc += a + b;
    }
    if (k < s1) acc += __half2float(Y[csr_tail[k] * 64 + lane]);
    acc *= 0.25f;                       // softmax(ones) = 0.25 exactly

    float sz = acc * acc;
    #pragma unroll
    for (int m = 1; m < 16; m <<= 1) sz += __shfl_xor(sz, m, 64);
    float zn = acc * rsqrtf(fmaxf(sz, 1e-12f));   // l2norm(Z1[h]) in regs

    float dacc = 0.f;
    for (k = s0; k < s1; ++k) {
        int t = csr_tail[k];
        float p = zn * __half2float(Tn[t * 64 + lane]);
        #pragma unroll
        for (int m = 1; m < 16; m <<= 1) p += __shfl_xor(p, m, 64);
        float mx = fmaxf(p, __shfl_xor(p, 16, 64));
        mx = fmaxf(mx, __shfl_xor(mx, 32, 64));
        float ev = __expf(p - mx);
        float se = ev + __shfl_xor(ev, 16, 64);
        se += __shfl_xor(se, 32, 64);
        float s = ev / se;
        if ((lane & 15) == 0) scores[k * 4 + i] = __float2half(s);
        dacc += s;
    }
    if ((lane & 15) == 0) deg[n * 4 + i] = dacc;
}

// Wave per node h: Z2 gather with scores (regs) -> out = 0.5*(X + dcol1*Z2).
__global__ void fused1(const int* __restrict__ offsets, const int* __restrict__ csr_tail,
                       const __half* __restrict__ Y, const __half* __restrict__ scores,
                       const float* __restrict__ dcol,
                       const float* __restrict__ Gu, const float* __restrict__ Gi,
                       float* __restrict__ out) {
    int n = blockIdx.x * 4 + (threadIdx.x >> 6);
    if (n >= NN) return;
    int lane = threadIdx.x & 63;
    int i = lane >> 4;
    int s0 = offsets[n], s1 = offsets[n + 1];

    float acc = 0.f;
    int k = s0;
    for (; k + 1 < s1; k += 2) {
        int t0 = csr_tail[k], t1 = csr_tail[k + 1];
        float sa = __half2float(scores[k * 4 + i]);
        float sb = __half2float(scores[(k + 1) * 4 + i]);
        float a = __half2float(Y[t0 * 64 + lane]);
        float b = __half2float(Y[t1 * 64 + lane]);
        acc += sa * a + sb * b;
    }
    if (k < s1) acc += __half2float(scores[k * 4 + i]) * __half2float(Y[csr_tail[k] * 64 + lane]);

    float x = getX(Gu, Gi, n, lane);
    out[n * 64 + lane] = 0.5f * (x + dcol[n * 4 + i] * acc);
}

// ---- launch ----

extern "C" void kernel_launch(void* const* d_in, const int* in_sizes, int n_in,
                              void* d_out, int out_size, void* d_ws, size_t ws_size,
                              hipStream_t stream) {
    const float* Gu = (const float*)d_in[0];
    const float* Gi = (const float*)d_in[1];
    const int* eh = (const int*)d_in[2];
    const int* et = (const int*)d_in[3];
    float* out = (float*)d_out;

    char* p = (char*)d_ws;
    int*    offsets  = (int*)p;        p += (size_t)(NN + 1) * 4;
    int*    deg0     = (int*)p;        p += (size_t)NN * 4;
    int*    cursor   = (int*)p;        p += (size_t)NN * 4;
    float*  deg      = (float*)p;      p += (size_t)NN * 4 * 4;
    float*  dcol     = (float*)p;      p += (size_t)NN * 4 * 4;
    int*    csr_tail = (int*)p;        p += (size_t)EE * 4;
    __half* scores   = (__half*)p;     p += (size_t)EE * 4 * 2;
    __half* Y        = (__half*)p;     p += (size_t)NN * 64 * 2;
    __half* Tn       = (__half*)p;     // total ~27.6 MB

    const int nk_blocks   = (NN * 64 + 255) / 256;
    const int edge_blocks = (EE + 255) / 256;
    const int n4_blocks   = (NN * 4 + 255) / 256;
    const int nw_blocks   = (NN + 3) / 4;   // wave-per-node

    // CSR build
    hipMemsetAsync(deg0, 0, NN * sizeof(int), stream);
    hipMemsetAsync(cursor, 0, NN * sizeof(int), stream);
    edge_count<<<edge_blocks, 256, 0, stream>>>(eh, deg0);
    scan_offsets<<<1, 1024, 0, stream>>>(deg0, offsets);
    edge_scatter<<<edge_blocks, 256, 0, stream>>>(eh, et, offsets, cursor, csr_tail);

    // iter 0 tables + fused propagate/attention
    prep0<<<nw_blocks, 256, 0, stream>>>(Gu, Gi, deg0, Tn, Y);
    fused0<<<nw_blocks, 256, 0, stream>>>(offsets, csr_tail, Y, Tn, scores, deg);

    // iter 1 propagate + finalize
    node_dcol1<<<n4_blocks, 256, 0, stream>>>(deg, dcol);
    build_Y1<<<nk_blocks, 256, 0, stream>>>(Gu, Gi, dcol, Y);
    fused1<<<nw_blocks, 256, 0, stream>>>(offsets, csr_tail, Y, scores, dcol, Gu, Gi, out);
}